// Round 4
// baseline (156.510 us; speedup 1.0000x reference)
//
#include <hip/hip_runtime.h>
#include <math.h>

#define BB 1024
#define S 32
#define DIM 64
#define NREL 237
#define SIGMA 0.1f

// ---- workspace layout (float offsets) ----
#define OFS_WR    0                       // 238*64  : Wr = relf_ext @ W_agg0 (row 237 = 0)
#define N_WR      (238*64)
#define OFS_WC0   (OFS_WR + N_WR)         // 64*237  : W_agg1 @ W_out[:237]
#define N_WC      (64*237)
#define OFS_WC1   (OFS_WC0 + N_WC)        // 64*237  : W_agg1 @ W_out[237:]
#define OFS_BC    (OFS_WC1 + N_WC)        // 237
#define OFS_HC    (OFS_BC + 237)          // 64

__device__ __forceinline__ float selu_f(float x) {
    const float alpha = 1.6732632423543772f;
    const float scale = 1.0507009873554805f;
    return scale * (x > 0.f ? x : alpha * expm1f(x));
}

// ---------- Kernel A: fold b-independent linear algebra (M1 eliminated) ----------
__global__ __launch_bounds__(256) void precompute_kernel(
    const float* __restrict__ rel_feat, const float* __restrict__ W0,
    const float* __restrict__ W1, const float* __restrict__ b1,
    const float* __restrict__ W_out, const float* __restrict__ b_out,
    const float* __restrict__ mW1, const float* __restrict__ mb1,
    float* __restrict__ ws) {
    __shared__ float red[256];
    int blk = blockIdx.x;
    const int tid = threadIdx.x;

    if (blk < 60) {                        // Wr[r][o], 64-deep
        int idx = blk * 256 + tid;
        if (idx < 238 * 64) {
            int r = idx >> 6, o = idx & 63;
            float acc = 0.f;
            if (r < NREL) {
#pragma unroll 8
                for (int d = 0; d < 64; ++d)
                    acc += rel_feat[r * 64 + d] * W0[d * 64 + o];
            }
            ws[OFS_WR + idx] = acc;        // row 237 stays 0
        }
        return;
    }
    blk -= 60;
    if (blk < 512) {                       // Wc0 / Wc1 : 64x237 each, 237-deep
        int half = blk >> 8;
        int lb = blk & 255;
        int o = lb >> 2, ct = lb & 3;
        int cl = tid & 63, g = tid >> 6;
        int c = ct * 64 + cl;
        const float* Wsrc = W_out + half * 237 * 237;
        float acc = 0.f;
        if (c < NREL) {
            int k0 = g * 60, k1 = (g == 3) ? 237 : (k0 + 60);
#pragma unroll 4
            for (int k = k0; k < k1; ++k)
                acc += W1[o * 237 + k] * Wsrc[k * 237 + c];
        }
        red[tid] = acc;
        __syncthreads();
        if (g == 0 && c < NREL) {
            float s = red[cl] + red[64 + cl] + red[128 + cl] + red[192 + cl];
            ws[(half ? OFS_WC1 : OFS_WC0) + o * 237 + c] = s;
        }
        return;
    }
    blk -= 512;
    if (blk < 4) {                         // bc[c]
        int cl = tid & 63, g = tid >> 6;
        int c = blk * 64 + cl;
        float acc = 0.f;
        if (c < NREL) {
            int k0 = g * 60, k1 = (g == 3) ? 237 : (k0 + 60);
#pragma unroll 4
            for (int k = k0; k < k1; ++k)
                acc += b1[k] * (W_out[k * 237 + c] + W_out[(237 + k) * 237 + c]);
        }
        red[tid] = acc;
        __syncthreads();
        if (g == 0 && c < NREL)
            ws[OFS_BC + c] = b_out[c] + red[cl] + red[64 + cl] + red[128 + cl] + red[192 + cl];
        return;
    }
    // hc[w]
    {
        int w = tid & 63, g = tid >> 6;
        int k0 = g * 60, k1 = (g == 3) ? 237 : (k0 + 60);
        float acc = 0.f;
#pragma unroll 4
        for (int k = k0; k < k1; ++k)
            acc += b1[k] * mW1[k * 64 + w];
        red[tid] = acc;
        __syncthreads();
        if (g == 0)
            ws[OFS_HC + w] = mb1[w] + red[w] + red[64 + w] + red[128 + w] + red[192 + w];
    }
}

// ---------- Kernel GF: gather + epilogue fused, 2 b's per block ----------
// 512 blocks x 76288 B LDS -> 2 blocks/CU, all resident.
// LDS map (floats):
//   [0,15232)      s_wr        (gather)   | aliased in final phase:
//   [15232,16256)  s_r2m (int)            |   [0,128)    s_omix
//   [16256,16384)  s_r1  (int)            |   [128,608)  s_ymix (2x240)
//   [16384,16512)  s_ent2(int)            |   [608,1088) s_out  (2x240)
//   [16512,16640)  s_m1                   |   [1088,1600) s_red (2x256)
//   [16640,18816)  s_v1 (32x68)           |   [1600,1728) s_h   (2x64)
//   [18816,19072)  s_ov (4x64) -- persists across phases
__global__ __launch_bounds__(256) void gf_kernel(
    const int* __restrict__ ep, const int* __restrict__ te_arr,
    const int* __restrict__ e2e_tab, const int* __restrict__ e2ent,
    const int* __restrict__ e2r, const float* __restrict__ b0,
    const float* __restrict__ t_arr, const float* __restrict__ eps,
    const float* __restrict__ W1, const float* __restrict__ mW1,
    const float* __restrict__ mW2, const float* __restrict__ mb2,
    const float* __restrict__ mW3, const float* __restrict__ mb3,
    const float* __restrict__ mW4, const float* __restrict__ mb4,
    const float* __restrict__ ws, float* __restrict__ out) {
    extern __shared__ float smem[];
    float* s_wr   = smem;
    int*   s_r2m  = (int*)(smem + 15232);
    int*   s_r1   = (int*)(smem + 16256);
    int*   s_ent2 = (int*)(smem + 16384);
    float* s_m1   = smem + 16512;
    float* s_v1   = smem + 16640;
    float* s_ov   = smem + 18816;

    const int tid = threadIdx.x;
    const int bb = blockIdx.x * 2;
    const int g = tid >> 4;
    const int c = tid & 15;
    const int te0 = te_arr[bb];
    const int te1 = te_arr[bb + 1];
    const float4 b0v = ((const float4*)b0)[c];

    // stage Wr into LDS
    {
        const float4* src = (const float4*)(ws + OFS_WR);
        float4* dst = (float4*)s_wr;
        for (int i = tid; i < 238 * 16; i += 256) dst[i] = src[i];
    }
    const float4* sWr4 = (const float4*)s_wr;

    // hoisted stage-1 for all 4 (b,side) units
    if (tid < 128) {
        int u = tid >> 5, s = tid & 31;
        int b = bb + (u >> 1), side = u & 1;
        int te = (u >> 1) ? te1 : te0;
        int ent = ep[b * 2 + side];
        int e1 = e2e_tab[ent * S + s];
        s_r1[u * 32 + s] = e2r[e1];
        s_m1[u * 32 + s] = (e1 != te) ? 1.0f : 0.0f;
        s_ent2[u * 32 + s] = e2ent[e1];
    }
    __syncthreads();

    // prologue: build r2m for unit 0
    {
        const int te = te0;
        for (int p = tid; p < 1024; p += 256) {
            int j = p >> 5, s = p & 31;
            int e2 = e2e_tab[s_ent2[j] * S + s];
            s_r2m[p] = (e2 == te) ? NREL : e2r[e2];
        }
    }
    __syncthreads();

    for (int u = 0; u < 4; ++u) {
        // sums: v1[j] = relu(self + mean(rows) + b0) * m1
        for (int jj = g; jj < 32; jj += 16) {
            float4 acc = sWr4[s_r1[u * 32 + jj] * 16 + c];
            float4 sa = make_float4(0.f, 0.f, 0.f, 0.f);
            float4 sb = make_float4(0.f, 0.f, 0.f, 0.f);
            const int* rr = &s_r2m[jj * 32];
#pragma unroll
            for (int s = 0; s < 16; ++s) {
                float4 v = sWr4[rr[s] * 16 + c];
                sa.x += v.x; sa.y += v.y; sa.z += v.z; sa.w += v.w;
            }
#pragma unroll
            for (int s = 16; s < 32; ++s) {
                float4 v = sWr4[rr[s] * 16 + c];
                sb.x += v.x; sb.y += v.y; sb.z += v.z; sb.w += v.w;
            }
            const float inv = 1.0f / 32.0f;
            float m = s_m1[u * 32 + jj];
            float4 r;
            r.x = fmaxf(acc.x + (sa.x + sb.x) * inv + b0v.x, 0.f) * m;
            r.y = fmaxf(acc.y + (sa.y + sb.y) * inv + b0v.y, 0.f) * m;
            r.z = fmaxf(acc.z + (sa.z + sb.z) * inv + b0v.z, 0.f) * m;
            r.w = fmaxf(acc.w + (sa.w + sb.w) * inv + b0v.w, 0.f) * m;
            *((float4*)&s_v1[jj * 68 + c * 4]) = r;
        }
        __syncthreads();
        // reduce (wave 0) + build r2m for u+1 (all threads) concurrently
        if (tid < 64) {
            float sum = 0.f;
#pragma unroll 8
            for (int j = 0; j < 32; ++j) sum += s_v1[j * 68 + tid];
            s_ov[u * 64 + tid] = sum * (1.0f / 32.0f);
        }
        if (u < 3) {
            const int un = u + 1;
            const int te = (un >> 1) ? te1 : te0;
            for (int p = tid; p < 1024; p += 256) {
                int j = p >> 5, s = p & 31;
                int e2 = e2e_tab[s_ent2[un * 32 + j] * S + s];
                s_r2m[p] = (e2 == te) ? NREL : e2r[e2];
            }
        }
        __syncthreads();
    }

    // ---------------- final phase (aliases s_wr region) ----------------
    float* s_omix = smem;          // 2*64
    float* s_ymix = smem + 128;    // 2*240
    float* s_out  = smem + 608;    // 2*240
    float* s_red  = smem + 1088;   // 2*256
    float* s_h    = smem + 1600;   // 2*64
    const float tb0v = t_arr[bb];
    const float tb1v = t_arr[bb + 1];
    const float* Wc0 = ws + OFS_WC0;
    const float* Wc1 = ws + OFS_WC1;
    const float* bc = ws + OFS_BC;
    const float* hc = ws + OFS_HC;

    if (tid < 128) {
        int p = tid >> 6, w = tid & 63;
        float tb = p ? tb1v : tb0v;
        float o0 = s_ov[(p * 2 + 0) * 64 + w];
        float o1 = s_ov[(p * 2 + 1) * 64 + w];
        s_omix[p * 64 + w] = (1.f - tb) * o0 + tb * o1;
    }
    __syncthreads();

    if (tid < NREL) {
        // ymix[p][k] = omix[p] @ W1[:,k]
        float y0 = 0.f, y1 = 0.f;
#pragma unroll 4
        for (int d = 0; d < 64; ++d) {
            float w1v = W1[d * 237 + tid];
            y0 += s_omix[d] * w1v;
            y1 += s_omix[64 + d] * w1v;
        }
        s_ymix[tid] = y0;
        s_ymix[240 + tid] = y1;
        // out[c] = bc + ov @ Wc  (both b's share weight loads)
        float a0 = bc[tid], a1 = a0;
#pragma unroll 4
        for (int d = 0; d < 64; ++d) {
            float w0 = Wc0[d * 237 + tid];
            float w1 = Wc1[d * 237 + tid];
            a0 += s_ov[d] * w0 + s_ov[64 + d] * w1;
            a1 += s_ov[128 + d] * w0 + s_ov[192 + d] * w1;
        }
        s_out[tid] = a0;
        s_out[240 + tid] = a1;
    }
    __syncthreads();

    // h1 partials: h[w] = Σ_k (σ·eps[k] + ymix[k]) · mW1[k,w]  (k-split by 4)
    {
        int w = tid & 63, gg = tid >> 6;
        float a0 = 0.f, a1 = 0.f;
        int k0 = gg * 60, k1 = (gg == 3) ? 237 : (k0 + 60);
        const float* e0 = eps + bb * 237;
        const float* e1 = eps + (bb + 1) * 237;
#pragma unroll 4
        for (int k = k0; k < k1; ++k) {
            float m = mW1[k * 64 + w];
            a0 += (SIGMA * e0[k] + s_ymix[k]) * m;
            a1 += (SIGMA * e1[k] + s_ymix[240 + k]) * m;
        }
        s_red[tid] = a0;
        s_red[256 + tid] = a1;
    }
    __syncthreads();
    if (tid < 128) {
        int p = tid >> 6, w = tid & 63;
        float tb = p ? tb1v : tb0v;
        float h = hc[w] + tb * mW1[237 * 64 + w]
                + s_red[p * 256 + w] + s_red[p * 256 + 64 + w]
                + s_red[p * 256 + 128 + w] + s_red[p * 256 + 192 + w];
        s_h[p * 64 + w] = selu_f(h);
    }
    __syncthreads();

    // h2
    {
        int w = tid & 63, gg = tid >> 6;
        float a0 = 0.f, a1 = 0.f;
#pragma unroll
        for (int d = gg * 16; d < gg * 16 + 16; ++d) {
            float m = mW2[d * 64 + w];
            a0 += s_h[d] * m;
            a1 += s_h[64 + d] * m;
        }
        s_red[tid] = a0;
        s_red[256 + tid] = a1;
    }
    __syncthreads();
    if (tid < 128) {
        int p = tid >> 6, w = tid & 63;
        float v = mb2[w] + s_red[p * 256 + w] + s_red[p * 256 + 64 + w]
                + s_red[p * 256 + 128 + w] + s_red[p * 256 + 192 + w];
        s_h[p * 64 + w] = selu_f(v);
    }
    __syncthreads();

    // h3
    {
        int w = tid & 63, gg = tid >> 6;
        float a0 = 0.f, a1 = 0.f;
#pragma unroll
        for (int d = gg * 16; d < gg * 16 + 16; ++d) {
            float m = mW3[d * 64 + w];
            a0 += s_h[d] * m;
            a1 += s_h[64 + d] * m;
        }
        s_red[tid] = a0;
        s_red[256 + tid] = a1;
    }
    __syncthreads();
    if (tid < 128) {
        int p = tid >> 6, w = tid & 63;
        float v = mb3[w] + s_red[p * 256 + w] + s_red[p * 256 + 64 + w]
                + s_red[p * 256 + 128 + w] + s_red[p * 256 + 192 + w];
        s_h[p * 64 + w] = selu_f(v);
    }
    __syncthreads();

    // vt[c] and final product
    if (tid < NREL) {
        float a0 = mb4[tid], a1 = a0;
#pragma unroll 4
        for (int w = 0; w < 64; ++w) {
            float m = mW4[w * 237 + tid];
            a0 += s_h[w] * m;
            a1 += s_h[64 + w] * m;
        }
        out[bb * 237 + tid] = s_out[tid] * a0;
        out[(bb + 1) * 237 + tid] = s_out[240 + tid] * a1;
    }
}

extern "C" void kernel_launch(void* const* d_in, const int* in_sizes, int n_in,
                              void* d_out, int out_size, void* d_ws, size_t ws_size,
                              hipStream_t stream) {
    const int* ep       = (const int*)d_in[0];
    const int* te       = (const int*)d_in[1];
    // d_in[2] = labels : dead code in the reference
    const int* e2e      = (const int*)d_in[3];
    const int* e2ent    = (const int*)d_in[4];
    const int* e2r      = (const int*)d_in[5];
    const float* t      = (const float*)d_in[6];
    const float* eps    = (const float*)d_in[7];
    const float* relf   = (const float*)d_in[8];
    const float* W0     = (const float*)d_in[9];
    const float* b0     = (const float*)d_in[10];
    const float* W1     = (const float*)d_in[11];
    const float* b1     = (const float*)d_in[12];
    const float* W_out  = (const float*)d_in[13];
    const float* b_out  = (const float*)d_in[14];
    const float* mW1    = (const float*)d_in[15];
    const float* mb1    = (const float*)d_in[16];
    const float* mW2    = (const float*)d_in[17];
    const float* mb2    = (const float*)d_in[18];
    const float* mW3    = (const float*)d_in[19];
    const float* mb3    = (const float*)d_in[20];
    const float* mW4    = (const float*)d_in[21];
    const float* mb4    = (const float*)d_in[22];
    float* ws  = (float*)d_ws;
    float* out = (float*)d_out;

    hipLaunchKernelGGL(precompute_kernel, dim3(577), dim3(256), 0, stream,
                       relf, W0, W1, b1, W_out, b_out, mW1, mb1, ws);
    hipLaunchKernelGGL(gf_kernel, dim3(BB / 2), dim3(256), 76288, stream,
                       ep, te, e2e, e2ent, e2r, b0,
                       t, eps, W1, mW1, mW2, mb2, mW3, mb3, mW4, mb4, ws, out);
}